// Round 7
// baseline (994.510 us; speedup 1.0000x reference)
//
#include <hip/hip_runtime.h>
#include <hip/hip_bf16.h>

#define BSZ 128
#define NSQ 1024
#define NSTEPC 8
#define IND 768
#define HIDD 512
#define G4D 2048
#define MLPD 512
#define KXD 1280
#define NEGV -100000.0f
#define KSG 16   // K-split chunks for gates gemm (1280/16 = 80 = 5 tiles)
#define MSPLIT 4 // m-split for scores kernel

typedef __attribute__((ext_vector_type(4))) float f32x4;
typedef __attribute__((ext_vector_type(8))) short short8v;

__device__ __forceinline__ void split2(float4 f0, float4 f1, short8v& hi, short8v& lo) {
  float fv[8] = {f0.x, f0.y, f0.z, f0.w, f1.x, f1.y, f1.z, f1.w};
#pragma unroll
  for (int j = 0; j < 8; ++j) {
    const unsigned ub = __builtin_bit_cast(unsigned, fv[j]);
    const unsigned hb = ub & 0xFFFF0000u;
    const float lf = fv[j] - __builtin_bit_cast(float, hb);
    hi[j] = (short)(hb >> 16);
    lo[j] = (short)(__builtin_bit_cast(unsigned, lf) >> 16);
  }
}

// tanh(x) = 1 - 2/(e^{2x}+1)
__device__ __forceinline__ float tanh_fast(float x) {
  x = fminf(fmaxf(x, -15.0f), 15.0f);
  float e = __builtin_amdgcn_exp2f(x * 2.8853900817779268f);
  float r = __builtin_amdgcn_rcpf(e + 1.0f);
  return fmaf(-2.0f, r, 1.0f);
}

// ---------------- one-time: split W1c into FRAGMENT-ORDER bf16 hi/lo planes.
// Wave (mx,wm), tile t, frag f, lane: 16B unit at
//   unit = (((mx*2+wm)*24 + t)*4 + f)*64 + l4*16 + l15
// element (row,k): mx=row>>7, wm=(row>>6)&1, f=(row>>4)&3, l15=row&15,
//                  t=k>>5, l4=(k>>3)&3, j=k&7
__global__ __launch_bounds__(256) void k_prep_wfrag(
    const float* __restrict__ W1c,
    unsigned short* __restrict__ wfh, unsigned short* __restrict__ wfl) {
  const int c = blockIdx.x * 256 + threadIdx.x;
  if (c >= 49152) return;  // 512 rows x 96 chunks of 8 k-elements
  const int row = c / 96, wc = c - row * 96;     // wc: t = wc>>2, l4 = wc&3
  const int mxwm = row >> 6;                     // mx*2+wm
  const int f = (row >> 4) & 3, l15 = row & 15;
  const int t = wc >> 2, l4 = wc & 3;
  const size_t unit = (((size_t)(mxwm * 24 + t) * 4 + f) * 64) + l4 * 16 + l15;
  const float* src = W1c + (size_t)row * IND + wc * 8;
  const float4 f0 = *(const float4*)src, f1 = *(const float4*)(src + 4);
  short8v hi, lo;
  split2(f0, f1, hi, lo);
  *(short8v*)(wfh + unit * 8) = hi;
  *(short8v*)(wfl + unit * 8) = lo;
}

// ---------------- init: mask from ctx_len, xh = [target_emb | 0], c=0, lp=0
__global__ __launch_bounds__(256) void k_init(
    const float* __restrict__ te, const int* __restrict__ cl,
    float* __restrict__ mask, float* __restrict__ xh,
    float* __restrict__ cst, float* __restrict__ lp) {
  const int b = blockIdx.x, tid = threadIdx.x;
  const int L = cl[b];
  for (int n = tid; n < NSQ; n += 256) mask[(size_t)b*NSQ + n] = (n >= L) ? NEGV : 0.0f;
  for (int d = tid; d < IND; d += 256) xh[(size_t)b*KXD + d] = te[(size_t)b*IND + d];
  for (int j = tid; j < HIDD; j += 256) {
    xh[(size_t)b*KXD + IND + j] = 0.0f;
    cst[(size_t)b*HIDD + j] = 0.0f;
  }
  if (tid == 0) lp[b] = 0.0f;
}

// ---------------- ctx_part GEMM, barrier-free / LDS-free:
// cp[b][m][n] = sum_k ctx[b,n,k]*W1c[m,k] + b1[m]; split-bf16 (hh+hl+lh)
// 256 thr / 4 independent waves (wm,wn); block tile m=128 x n=128; wave 64x64.
// A-frags: coalesced dwordx4 from fragment-order planes (direct to VGPR).
// B-frags: direct ctx reads (lane -> 32B at [rc][t*32+l4*8]), split in regs.
__global__ __launch_bounds__(256) void k_ctx6(
    const float* __restrict__ ctx,
    const unsigned short* __restrict__ wfh, const unsigned short* __restrict__ wfl,
    const float* __restrict__ bias, const int* __restrict__ clen,
    float* __restrict__ cp) {
  // bijective XCD swizzle: all 4 m-blocks of a ctx row-block share one XCD's L2
  const int bid = blockIdx.x;
  const int v = ((bid & 7) << 9) + (bid >> 3);
  const int mx = v & 3;          // m-block (4)
  const int rbC = v >> 2;        // ctx row-block (1024)
  const int b = rbC >> 3;
  const int nbase = (rbC & 7) << 7;
  if (nbase >= clen[b]) return;  // masked region: cp never read there
  const int i0 = rbC << 7;
  const int m0 = mx << 7;
  const int tid = threadIdx.x;
  const int lane = tid & 63, wid = tid >> 6;
  const int wm = wid & 1, wn = wid >> 1;
  const int l15 = lane & 15, l4 = lane >> 4;

  // per-wave W-frag base (shorts): (((mx*2+wm)*24 + t)*4 + f)*512 + lane*8
  const size_t wbase = (size_t)((mx * 2 + wm) * 24) * 2048 + lane * 8;
  // per-wave ctx fragment row pointers (f=0..3): row = i0 + wn*64 + f*16 + l15
  const float* cbase = ctx + (size_t)(i0 + wn * 64 + l15) * IND + l4 * 8;

  f32x4 acc[4][4] = {};  // [fm][fn]
  for (int t = 0; t < 24; ++t) {
    // B-frags: direct read + in-reg split
    short8v bh[4], bl[4];
#pragma unroll
    for (int f = 0; f < 4; ++f) {
      const float* s = cbase + (size_t)(f * 16) * IND + t * 32;
      split2(*(const float4*)s, *(const float4*)(s + 4), bh[f], bl[f]);
    }
    // A-frags: coalesced fragment-order loads
    short8v ah[4], al[4];
    const size_t toff = wbase + (size_t)t * 2048;
#pragma unroll
    for (int f = 0; f < 4; ++f) {
      ah[f] = *(const short8v*)(wfh + toff + f * 512);
      al[f] = *(const short8v*)(wfl + toff + f * 512);
    }
#pragma unroll
    for (int fm = 0; fm < 4; ++fm)
#pragma unroll
      for (int fn = 0; fn < 4; ++fn) {
        acc[fm][fn] = __builtin_amdgcn_mfma_f32_16x16x32_bf16(ah[fm], bh[fn], acc[fm][fn], 0, 0, 0);
        acc[fm][fn] = __builtin_amdgcn_mfma_f32_16x16x32_bf16(ah[fm], bl[fn], acc[fm][fn], 0, 0, 0);
        acc[fm][fn] = __builtin_amdgcn_mfma_f32_16x16x32_bf16(al[fm], bh[fn], acc[fm][fn], 0, 0, 0);
      }
  }
  // epilogue: D row m = (l>>4)*4 + reg, col n = l&15 (16-lane 64B segments)
#pragma unroll
  for (int fm = 0; fm < 4; ++fm) {
#pragma unroll
    for (int r = 0; r < 4; ++r) {
      const int m = m0 + wm * 64 + fm * 16 + l4 * 4 + r;
      const float bb = bias[m];
      float* dst = cp + (((size_t)(b * MLPD + m)) << 10) + nbase + wn * 64 + l15;
#pragma unroll
      for (int fn = 0; fn < 4; ++fn)
        dst[fn * 16] = acc[fm][fn][r] + bb;
    }
  }
}

// ---------------- K-split partial GEMM (gates): P[kc][i][n] = sum_{k in chunk} A[i,k]*B(n,k)
__global__ __launch_bounds__(256) void k_pgemm(
    const float* __restrict__ A, int lda, int acol,
    const float* __restrict__ B0, int ldb0, int kb,
    const float* __restrict__ B1, int ldb1,
    int kTiles, int N, float* __restrict__ P) {
  __shared__ float As[16][128];
  __shared__ float Bs[16][132];
  const int n0 = blockIdx.x * 128;
  const int kc0 = blockIdx.y * kTiles * 16;
  const int tid = threadIdx.x;
  const int tn = tid & 15;   // n-group
  const int ta = tid >> 4;   // i-group
  float acc[8][8] = {};      // [ri][ni]
  for (int t = 0; t < kTiles; ++t) {
    const int k0 = kc0 + t * 16;
#pragma unroll
    for (int u = 0; u < 2; ++u) {
      const int v = tid + u * 256;
      const int r = v >> 2, kc = v & 3;
      const float4 a4 = *(const float4*)(A + (size_t)r * lda + acol + k0 + kc * 4);
      As[kc*4+0][r] = a4.x; As[kc*4+1][r] = a4.y; As[kc*4+2][r] = a4.z; As[kc*4+3][r] = a4.w;
      const float* bp = (k0 < kb) ? (B0 + (size_t)(n0 + r) * ldb0 + k0 + kc * 4)
                                  : (B1 + (size_t)(n0 + r) * ldb1 + (k0 - kb) + kc * 4);
      const float4 b4 = *(const float4*)bp;
      Bs[kc*4+0][r] = b4.x; Bs[kc*4+1][r] = b4.y; Bs[kc*4+2][r] = b4.z; Bs[kc*4+3][r] = b4.w;
    }
    __syncthreads();
#pragma unroll
    for (int kk = 0; kk < 16; ++kk) {
      float av[8], bv[8];
#pragma unroll
      for (int q = 0; q < 8; ++q) av[q] = As[kk][ta*8+q];
#pragma unroll
      for (int q = 0; q < 8; ++q) bv[q] = Bs[kk][tn*8+q];
#pragma unroll
      for (int ri = 0; ri < 8; ++ri)
#pragma unroll
        for (int ni = 0; ni < 8; ++ni)
          acc[ri][ni] = fmaf(av[ri], bv[ni], acc[ri][ni]);
    }
    __syncthreads();
  }
#pragma unroll
  for (int ri = 0; ri < 8; ++ri) {
    const int i = ta * 8 + ri;
    float* p = P + ((size_t)blockIdx.y * BSZ + i) * N + n0 + tn * 8;
    *(float4*)(p + 0) = make_float4(acc[ri][0], acc[ri][1], acc[ri][2], acc[ri][3]);
    *(float4*)(p + 4) = make_float4(acc[ri][4], acc[ri][5], acc[ri][6], acc[ri][7]);
  }
}

// ---------------- gate reduce + LSTM + xh h-write + FUSED hproj
__global__ __launch_bounds__(512) void k_lstm2f(
    const float* __restrict__ gp, const float* __restrict__ b_ih,
    const float* __restrict__ b_hh, const float* __restrict__ W1h,
    float* __restrict__ cst, float* __restrict__ xh, float* __restrict__ hpp) {
  __shared__ float hs[HIDD];
  const int b = blockIdx.x, j = threadIdx.x;
  float g[4];
#pragma unroll
  for (int q = 0; q < 4; ++q) {
    float s = b_ih[q*HIDD + j] + b_hh[q*HIDD + j];
#pragma unroll
    for (int ks = 0; ks < KSG; ++ks) s += gp[((size_t)ks*BSZ + b)*G4D + q*HIDD + j];
    g[q] = s;
  }
  const float c_old = cst[(size_t)b*HIDD + j];
  const float ig = 1.0f / (1.0f + expf(-g[0]));
  const float fg = 1.0f / (1.0f + expf(-g[1]));
  const float gg = tanhf(g[2]);
  const float og = 1.0f / (1.0f + expf(-g[3]));
  const float cn = fg * c_old + ig * gg;
  const float hn = og * tanhf(cn);
  cst[(size_t)b*HIDD + j] = cn;
  xh[(size_t)b*KXD + IND + j] = hn;
  hs[j] = hn;
  __syncthreads();
  // fused hproj: hpp[b][m] = sum_k h[k] * W1h[m][k], m = j (W1h is L2-hot, 1MB)
  const float* wr = W1h + (size_t)j * HIDD;
  float s = 0.0f;
#pragma unroll 4
  for (int k = 0; k < HIDD; k += 4) {
    const float4 h4 = *(const float4*)&hs[k];
    const float4 w4 = *(const float4*)&wr[k];
    s = fmaf(h4.x, w4.x, fmaf(h4.y, w4.y, fmaf(h4.z, w4.z, fmaf(h4.w, w4.w, s))));
  }
  hpp[(size_t)b * HIDD + j] = s;
}

// ---------------- scores partial: psc[b][mh][n] = sum_{m in mh-range} tanh(cp+hp)*w2
__global__ __launch_bounds__(256) void k_scores(
    const float* __restrict__ cp, const float* __restrict__ hpp,
    const float* __restrict__ w2, const int* __restrict__ clen,
    float* __restrict__ psc) {
  const int mh = blockIdx.x;  // [0,MSPLIT)
  const int b = blockIdx.y;
  const int tid = threadIdx.x;
  __shared__ float hs[128], ws[128];
  if (tid < 128) {
    hs[tid] = hpp[(size_t)b * MLPD + mh * 128 + tid];
    ws[tid] = w2[mh * 128 + tid];
  }
  __syncthreads();
  const int len = clen[b];
  const int n0 = tid * 4;
  if (n0 >= len) return;
  float ax = 0, ay = 0, az = 0, aw = 0;
  const float* base = cp + ((size_t)b * MLPD + mh * 128) * NSQ + n0;
#pragma unroll 4
  for (int mm = 0; mm < 128; ++mm) {
    const float4 c4 = *(const float4*)(base + (size_t)mm * NSQ);
    const float h = hs[mm], w = ws[mm];
    ax = fmaf(tanh_fast(c4.x + h), w, ax);
    ay = fmaf(tanh_fast(c4.y + h), w, ay);
    az = fmaf(tanh_fast(c4.z + h), w, az);
    aw = fmaf(tanh_fast(c4.w + h), w, aw);
  }
  *(float4*)(psc + ((size_t)b * MSPLIT + mh) * NSQ + n0) = make_float4(ax, ay, az, aw);
}

// ---------------- argmax + LSE + lp + mask/x update (one block per batch row)
__global__ __launch_bounds__(256) void k_argmax(
    const float* __restrict__ psc, float* __restrict__ mask,
    const float* __restrict__ gum, const float* __restrict__ b2p,
    float* __restrict__ lp, const float* __restrict__ ctx,
    float* __restrict__ xh, float* __restrict__ outv, int step) {
  const int b = blockIdx.x, tid = threadIdx.x;
  __shared__ float rv[256], rs[256], rm[256];
  __shared__ int ri[256];
  __shared__ int sel;
  const float b2 = b2p[0];
  const int n0 = tid * 4;
  const float4 m4 = *(const float4*)(mask + (size_t)b * NSQ + n0);
  float sc[4] = {b2 + m4.x, b2 + m4.y, b2 + m4.z, b2 + m4.w};
#pragma unroll
  for (int mh = 0; mh < MSPLIT; ++mh) {
    const float4 p4 = *(const float4*)(psc + ((size_t)b * MSPLIT + mh) * NSQ + n0);
    sc[0] += p4.x; sc[1] += p4.y; sc[2] += p4.z; sc[3] += p4.w;
  }
  const float4 g4 = *(const float4*)(gum + ((size_t)step * BSZ + b) * NSQ + n0);
  const float gv[4] = {g4.x, g4.y, g4.z, g4.w};
  float bestv = -1e30f, bests = 0.0f, msc = -1e30f;
  int bestn = 0;
#pragma unroll
  for (int q = 0; q < 4; ++q) {
    const float v = sc[q] + gv[q];
    if (v > bestv) { bestv = v; bestn = n0 + q; bests = sc[q]; }
    msc = fmaxf(msc, sc[q]);
  }
  rv[tid] = bestv; ri[tid] = bestn; rs[tid] = bests; rm[tid] = msc;
  __syncthreads();
  for (int o = 128; o > 0; o >>= 1) {
    if (tid < o) {
      if (rv[tid+o] > rv[tid] || (rv[tid+o] == rv[tid] && ri[tid+o] < ri[tid])) {
        rv[tid] = rv[tid+o]; ri[tid] = ri[tid+o]; rs[tid] = rs[tid+o];
      }
      rm[tid] = fmaxf(rm[tid], rm[tid+o]);
    }
    __syncthreads();
  }
  const float M = rm[0];
  __syncthreads();
  float se = 0.0f;
#pragma unroll
  for (int q = 0; q < 4; ++q)
    se += __builtin_amdgcn_exp2f((sc[q] - M) * 1.4426950408889634f);
  rm[tid] = se;
  __syncthreads();
  for (int o = 128; o > 0; o >>= 1) {
    if (tid < o) rm[tid] += rm[tid+o];
    __syncthreads();
  }
  if (tid == 0) {
    const int n = ri[0];
    const float lse = M + logf(rm[0]);
    const float nlp = lp[b] + rs[0] - lse;
    lp[b] = nlp;
    mask[(size_t)b * NSQ + n] = NEGV;
    outv[step * BSZ + b] = (float)n;
    if (step == NSTEPC - 1) outv[NSTEPC * BSZ + b] = nlp;
    sel = n;
  }
  __syncthreads();
  const int n = sel;
  const float4* src = (const float4*)(ctx + ((size_t)b * NSQ + n) * IND);
  float4* dst = (float4*)(xh + (size_t)b * KXD);
  for (int d = tid; d < IND / 4; d += 256) dst[d] = src[d];
}

extern "C" void kernel_launch(void* const* d_in, const int* in_sizes, int n_in,
                              void* d_out, int out_size, void* d_ws, size_t ws_size,
                              hipStream_t stream) {
  const float* target_emb = (const float*)d_in[0];
  const float* ctx_emb   = (const float*)d_in[1];
  const int*   ctx_len   = (const int*)d_in[3];
  const float* W_ih = (const float*)d_in[5];
  const float* W_hh = (const float*)d_in[6];
  const float* b_ih = (const float*)d_in[7];
  const float* b_hh = (const float*)d_in[8];
  const float* W1c  = (const float*)d_in[9];
  const float* W1h  = (const float*)d_in[10];
  const float* b1   = (const float*)d_in[11];
  const float* w2   = (const float*)d_in[12];
  const float* b2   = (const float*)d_in[13];
  const float* gumbel = (const float*)d_in[14];
  float* out = (float*)d_out;

  float* ws = (float*)d_ws;
  size_t off = 0;
  auto alloc = [&](size_t n) { float* p = ws + off; off += (n + 63) & ~(size_t)63; return p; };

  float* cp   = alloc((size_t)BSZ * MLPD * NSQ);   // 268 MB
  float* gp   = alloc((size_t)KSG * BSZ * G4D);
  float* hpp  = alloc((size_t)BSZ * MLPD);
  float* psc  = alloc((size_t)BSZ * MSPLIT * NSQ);
  float* mask = alloc((size_t)BSZ * NSQ);
  float* xh   = alloc((size_t)BSZ * KXD);
  float* cst  = alloc((size_t)BSZ * HIDD);
  float* lp   = alloc(128);
  unsigned short* wfh = (unsigned short*)alloc(196608);   // 512x768 u16, frag-order
  unsigned short* wfl = (unsigned short*)alloc(196608);

  k_prep_wfrag<<<192, 256, 0, stream>>>(W1c, wfh, wfl);
  k_init<<<BSZ, 256, 0, stream>>>(target_emb, ctx_len, mask, xh, cst, lp);
  k_ctx6<<<4096, 256, 0, stream>>>(ctx_emb, wfh, wfl, b1, ctx_len, cp);

  for (int t = 0; t < NSTEPC; ++t) {
    // gates partials: N=2048, K=1280 split in 16 chunks of 5 tiles
    k_pgemm<<<dim3(G4D/128, KSG), 256, 0, stream>>>(
        xh, KXD, 0, W_ih, IND, IND, W_hh, HIDD, 5, G4D, gp);
    k_lstm2f<<<BSZ, 512, 0, stream>>>(gp, b_ih, b_hh, W1h, cst, xh, hpp);
    k_scores<<<dim3(MSPLIT, BSZ), 256, 0, stream>>>(cp, hpp, w2, ctx_len, psc);
    k_argmax<<<BSZ, 256, 0, stream>>>(psc, mask, gumbel, b2, lp, ctx_emb, xh, out, t);
  }
}

// Round 8
// 850.854 us; speedup vs baseline: 1.1688x; 1.1688x over previous
//
#include <hip/hip_runtime.h>
#include <hip/hip_bf16.h>

#define BSZ 128
#define NSQ 1024
#define NSTEPC 8
#define IND 768
#define HIDD 512
#define G4D 2048
#define MLPD 512
#define KXD 1280
#define NEGV -100000.0f
#define KSG 16   // K-split chunks for gates gemm (1280/16 = 80 = 5 tiles)
#define KSH 8    // K-split chunks for hproj gemm (512/8 = 64 = 4 tiles)
#define MSPLIT 4 // m-split for scores kernel

typedef __attribute__((ext_vector_type(4))) float f32x4;
typedef __attribute__((ext_vector_type(8))) short short8v;

__device__ __forceinline__ void split2(float4 f0, float4 f1, short8v& hi, short8v& lo) {
  float fv[8] = {f0.x, f0.y, f0.z, f0.w, f1.x, f1.y, f1.z, f1.w};
#pragma unroll
  for (int j = 0; j < 8; ++j) {
    const unsigned ub = __builtin_bit_cast(unsigned, fv[j]);
    const unsigned hb = ub & 0xFFFF0000u;
    const float lf = fv[j] - __builtin_bit_cast(float, hb);
    hi[j] = (short)(hb >> 16);
    lo[j] = (short)(__builtin_bit_cast(unsigned, lf) >> 16);
  }
}

// tanh(x) = 1 - 2/(e^{2x}+1)
__device__ __forceinline__ float tanh_fast(float x) {
  x = fminf(fmaxf(x, -15.0f), 15.0f);
  float e = __builtin_amdgcn_exp2f(x * 2.8853900817779268f);
  float r = __builtin_amdgcn_rcpf(e + 1.0f);
  return fmaf(-2.0f, r, 1.0f);
}

// ---------------- one-time: split W1c into FRAGMENT-ORDER bf16 hi/lo planes.
// unit16B = (((mx*2+wm)*24 + t)*4 + f)*64 + l4*16 + l15
__global__ __launch_bounds__(256) void k_prep_wfrag(
    const float* __restrict__ W1c,
    unsigned short* __restrict__ wfh, unsigned short* __restrict__ wfl) {
  const int c = blockIdx.x * 256 + threadIdx.x;
  if (c >= 49152) return;  // 512 rows x 96 chunks of 8 k-elements
  const int row = c / 96, wc = c - row * 96;
  const int mxwm = row >> 6;
  const int f = (row >> 4) & 3, l15 = row & 15;
  const int t = wc >> 2, l4 = wc & 3;
  const size_t unit = (((size_t)(mxwm * 24 + t) * 4 + f) * 64) + l4 * 16 + l15;
  const float* src = W1c + (size_t)row * IND + wc * 8;
  const float4 f0 = *(const float4*)src, f1 = *(const float4*)(src + 4);
  short8v hi, lo;
  split2(f0, f1, hi, lo);
  *(short8v*)(wfh + unit * 8) = hi;
  *(short8v*)(wfl + unit * 8) = lo;
}

// ---------------- init: mask from ctx_len, xh = [target_emb | 0], c=0, lp=0
__global__ __launch_bounds__(256) void k_init(
    const float* __restrict__ te, const int* __restrict__ cl,
    float* __restrict__ mask, float* __restrict__ xh,
    float* __restrict__ cst, float* __restrict__ lp) {
  const int b = blockIdx.x, tid = threadIdx.x;
  const int L = cl[b];
  for (int n = tid; n < NSQ; n += 256) mask[(size_t)b*NSQ + n] = (n >= L) ? NEGV : 0.0f;
  for (int d = tid; d < IND; d += 256) xh[(size_t)b*KXD + d] = te[(size_t)b*IND + d];
  for (int j = tid; j < HIDD; j += 256) {
    xh[(size_t)b*KXD + IND + j] = 0.0f;
    cst[(size_t)b*HIDD + j] = 0.0f;
  }
  if (tid == 0) lp[b] = 0.0f;
}

// ---------------- build compacted active row-block list (deterministic scan)
// meta[0] = nact; meta[1..nact] = active rbC indices (ascending)
__global__ __launch_bounds__(256) void k_active(
    const int* __restrict__ clen, int* __restrict__ meta) {
  __shared__ int cnt[256];
  const int tid = threadIdx.x;
  int f[4], c = 0;
#pragma unroll
  for (int j = 0; j < 4; ++j) {
    const int rb = tid * 4 + j;
    f[j] = (((rb & 7) << 7) < clen[rb >> 3]) ? 1 : 0;
    c += f[j];
  }
  cnt[tid] = c;
  __syncthreads();
  for (int o = 1; o < 256; o <<= 1) {
    int v = 0;
    if (tid >= o) v = cnt[tid - o];
    __syncthreads();
    if (tid >= o) cnt[tid] += v;
    __syncthreads();
  }
  int pos = cnt[tid] - c;  // exclusive prefix
#pragma unroll
  for (int j = 0; j < 4; ++j)
    if (f[j]) meta[1 + pos++] = tid * 4 + j;
  if (tid == 255) meta[0] = cnt[255];
}

// ---------------- ctx_part GEMM, persistent grid-stride, LDS/barrier-free:
// cp[b][m][n] = sum_k ctx[b,n,k]*W1c[m,k] + b1[m]; split-bf16 (hh+hl+lh)
// 1024 persistent blocks x 256 thr (4 independent waves); item = (rb, mx);
// block tile m=128 x n=128, wave 64x64; A-frags coalesced from frag-order
// planes, B-frags direct ctx reads split in regs. Inner body = verified ctx6.
__global__ __launch_bounds__(256) void k_ctx7(
    const float* __restrict__ ctx,
    const unsigned short* __restrict__ wfh, const unsigned short* __restrict__ wfl,
    const float* __restrict__ bias, const int* __restrict__ meta,
    float* __restrict__ cp) {
  const int tid = threadIdx.x;
  const int lane = tid & 63, wid = tid >> 6;
  const int wm = wid & 1, wn = wid >> 1;
  const int l15 = lane & 15, l4 = lane >> 4;
  const int nwork = meta[0] * 4;

  for (int w = blockIdx.x; w < nwork; w += gridDim.x) {
    const int rb = meta[1 + (w >> 2)];
    const int mx = w & 3;
    const int b = rb >> 3;
    const int nbase = (rb & 7) << 7;
    const int i0 = rb << 7;
    const int m0 = mx << 7;
    const size_t wbase = (size_t)((mx * 2 + wm) * 24) * 2048 + lane * 8;
    const float* cbase = ctx + (size_t)(i0 + wn * 64 + l15) * IND + l4 * 8;

    f32x4 acc[4][4] = {};  // [fm][fn]
    for (int t = 0; t < 24; ++t) {
      // B-frags: direct read + in-reg split
      short8v bh[4], bl[4];
#pragma unroll
      for (int f = 0; f < 4; ++f) {
        const float* s = cbase + (size_t)(f * 16) * IND + t * 32;
        split2(*(const float4*)s, *(const float4*)(s + 4), bh[f], bl[f]);
      }
      // A-frags: coalesced fragment-order loads
      short8v ah[4], al[4];
      const size_t toff = wbase + (size_t)t * 2048;
#pragma unroll
      for (int f = 0; f < 4; ++f) {
        ah[f] = *(const short8v*)(wfh + toff + f * 512);
        al[f] = *(const short8v*)(wfl + toff + f * 512);
      }
#pragma unroll
      for (int fm = 0; fm < 4; ++fm)
#pragma unroll
        for (int fn = 0; fn < 4; ++fn) {
          acc[fm][fn] = __builtin_amdgcn_mfma_f32_16x16x32_bf16(ah[fm], bh[fn], acc[fm][fn], 0, 0, 0);
          acc[fm][fn] = __builtin_amdgcn_mfma_f32_16x16x32_bf16(ah[fm], bl[fn], acc[fm][fn], 0, 0, 0);
          acc[fm][fn] = __builtin_amdgcn_mfma_f32_16x16x32_bf16(al[fm], bh[fn], acc[fm][fn], 0, 0, 0);
        }
    }
    // epilogue: D row m = (l>>4)*4 + reg, col n = l&15
#pragma unroll
    for (int fm = 0; fm < 4; ++fm) {
#pragma unroll
      for (int r = 0; r < 4; ++r) {
        const int m = m0 + wm * 64 + fm * 16 + l4 * 4 + r;
        const float bb = bias[m];
        float* dst = cp + (((size_t)(b * MLPD + m)) << 10) + nbase + wn * 64 + l15;
#pragma unroll
        for (int fn = 0; fn < 4; ++fn)
          dst[fn * 16] = acc[fm][fn][r] + bb;
      }
    }
  }
}

// ---------------- K-split partial GEMM: P[kc][i][n] = sum_{k in chunk} A[i,k]*B(n,k)
__global__ __launch_bounds__(256) void k_pgemm(
    const float* __restrict__ A, int lda, int acol,
    const float* __restrict__ B0, int ldb0, int kb,
    const float* __restrict__ B1, int ldb1,
    int kTiles, int N, float* __restrict__ P) {
  __shared__ float As[16][128];
  __shared__ float Bs[16][132];
  const int n0 = blockIdx.x * 128;
  const int kc0 = blockIdx.y * kTiles * 16;
  const int tid = threadIdx.x;
  const int tn = tid & 15;   // n-group
  const int ta = tid >> 4;   // i-group
  float acc[8][8] = {};      // [ri][ni]
  for (int t = 0; t < kTiles; ++t) {
    const int k0 = kc0 + t * 16;
#pragma unroll
    for (int u = 0; u < 2; ++u) {
      const int v = tid + u * 256;
      const int r = v >> 2, kc = v & 3;
      const float4 a4 = *(const float4*)(A + (size_t)r * lda + acol + k0 + kc * 4);
      As[kc*4+0][r] = a4.x; As[kc*4+1][r] = a4.y; As[kc*4+2][r] = a4.z; As[kc*4+3][r] = a4.w;
      const float* bp = (k0 < kb) ? (B0 + (size_t)(n0 + r) * ldb0 + k0 + kc * 4)
                                  : (B1 + (size_t)(n0 + r) * ldb1 + (k0 - kb) + kc * 4);
      const float4 b4 = *(const float4*)bp;
      Bs[kc*4+0][r] = b4.x; Bs[kc*4+1][r] = b4.y; Bs[kc*4+2][r] = b4.z; Bs[kc*4+3][r] = b4.w;
    }
    __syncthreads();
#pragma unroll
    for (int kk = 0; kk < 16; ++kk) {
      float av[8], bv[8];
#pragma unroll
      for (int q = 0; q < 8; ++q) av[q] = As[kk][ta*8+q];
#pragma unroll
      for (int q = 0; q < 8; ++q) bv[q] = Bs[kk][tn*8+q];
#pragma unroll
      for (int ri = 0; ri < 8; ++ri)
#pragma unroll
        for (int ni = 0; ni < 8; ++ni)
          acc[ri][ni] = fmaf(av[ri], bv[ni], acc[ri][ni]);
    }
    __syncthreads();
  }
#pragma unroll
  for (int ri = 0; ri < 8; ++ri) {
    const int i = ta * 8 + ri;
    float* p = P + ((size_t)blockIdx.y * BSZ + i) * N + n0 + tn * 8;
    *(float4*)(p + 0) = make_float4(acc[ri][0], acc[ri][1], acc[ri][2], acc[ri][3]);
    *(float4*)(p + 4) = make_float4(acc[ri][4], acc[ri][5], acc[ri][6], acc[ri][7]);
  }
}

// ---------------- reduce gate partials + LSTM cell update (writes c, xh h-part)
__global__ __launch_bounds__(512) void k_lstm(
    const float* __restrict__ gp, const float* __restrict__ b_ih,
    const float* __restrict__ b_hh, float* __restrict__ cst, float* __restrict__ xh) {
  const int b = blockIdx.x, j = threadIdx.x;
  float g[4];
#pragma unroll
  for (int q = 0; q < 4; ++q) {
    float s = b_ih[q*HIDD + j] + b_hh[q*HIDD + j];
#pragma unroll
    for (int ks = 0; ks < KSG; ++ks) s += gp[((size_t)ks*BSZ + b)*G4D + q*HIDD + j];
    g[q] = s;
  }
  const float c_old = cst[(size_t)b*HIDD + j];
  const float ig = 1.0f / (1.0f + expf(-g[0]));
  const float fg = 1.0f / (1.0f + expf(-g[1]));
  const float gg = tanhf(g[2]);
  const float og = 1.0f / (1.0f + expf(-g[3]));
  const float cn = fg * c_old + ig * gg;
  const float hn = og * tanhf(cn);
  cst[(size_t)b*HIDD + j] = cn;
  xh[(size_t)b*KXD + IND + j] = hn;
}

// ---------------- scores partial: psc[b][mh][n] = sum_{m in mh-range} tanh(cp+hp)*w2
__global__ __launch_bounds__(256) void k_scores(
    const float* __restrict__ cp, const float* __restrict__ hpp,
    const float* __restrict__ w2, const int* __restrict__ clen,
    float* __restrict__ psc) {
  const int mh = blockIdx.x;  // [0,MSPLIT)
  const int b = blockIdx.y;
  const int tid = threadIdx.x;
  __shared__ float hs[128], ws[128];
  if (tid < 128) {
    const int m = mh * 128 + tid;
    float s = 0.0f;
#pragma unroll
    for (int ks = 0; ks < KSH; ++ks) s += hpp[((size_t)ks*BSZ + b)*MLPD + m];
    hs[tid] = s;
    ws[tid] = w2[m];
  }
  __syncthreads();
  const int len = clen[b];
  const int n0 = tid * 4;
  if (n0 >= len) return;
  float ax = 0, ay = 0, az = 0, aw = 0;
  const float* base = cp + ((size_t)b * MLPD + mh * 128) * NSQ + n0;
#pragma unroll 4
  for (int mm = 0; mm < 128; ++mm) {
    const float4 c4 = *(const float4*)(base + (size_t)mm * NSQ);
    const float h = hs[mm], w = ws[mm];
    ax = fmaf(tanh_fast(c4.x + h), w, ax);
    ay = fmaf(tanh_fast(c4.y + h), w, ay);
    az = fmaf(tanh_fast(c4.z + h), w, az);
    aw = fmaf(tanh_fast(c4.w + h), w, aw);
  }
  *(float4*)(psc + ((size_t)b * MSPLIT + mh) * NSQ + n0) = make_float4(ax, ay, az, aw);
}

// ---------------- argmax + LSE + lp + mask/x update (one block per batch row)
__global__ __launch_bounds__(256) void k_argmax(
    const float* __restrict__ psc, float* __restrict__ mask,
    const float* __restrict__ gum, const float* __restrict__ b2p,
    float* __restrict__ lp, const float* __restrict__ ctx,
    float* __restrict__ xh, float* __restrict__ outv, int step) {
  const int b = blockIdx.x, tid = threadIdx.x;
  __shared__ float rv[256], rs[256], rm[256];
  __shared__ int ri[256];
  __shared__ int sel;
  const float b2 = b2p[0];
  const int n0 = tid * 4;
  const float4 m4 = *(const float4*)(mask + (size_t)b * NSQ + n0);
  float sc[4] = {b2 + m4.x, b2 + m4.y, b2 + m4.z, b2 + m4.w};
#pragma unroll
  for (int mh = 0; mh < MSPLIT; ++mh) {
    const float4 p4 = *(const float4*)(psc + ((size_t)b * MSPLIT + mh) * NSQ + n0);
    sc[0] += p4.x; sc[1] += p4.y; sc[2] += p4.z; sc[3] += p4.w;
  }
  const float4 g4 = *(const float4*)(gum + ((size_t)step * BSZ + b) * NSQ + n0);
  const float gv[4] = {g4.x, g4.y, g4.z, g4.w};
  float bestv = -1e30f, bests = 0.0f, msc = -1e30f;
  int bestn = 0;
#pragma unroll
  for (int q = 0; q < 4; ++q) {
    const float v = sc[q] + gv[q];
    if (v > bestv) { bestv = v; bestn = n0 + q; bests = sc[q]; }
    msc = fmaxf(msc, sc[q]);
  }
  rv[tid] = bestv; ri[tid] = bestn; rs[tid] = bests; rm[tid] = msc;
  __syncthreads();
  for (int o = 128; o > 0; o >>= 1) {
    if (tid < o) {
      if (rv[tid+o] > rv[tid] || (rv[tid+o] == rv[tid] && ri[tid+o] < ri[tid])) {
        rv[tid] = rv[tid+o]; ri[tid] = ri[tid+o]; rs[tid] = rs[tid+o];
      }
      rm[tid] = fmaxf(rm[tid], rm[tid+o]);
    }
    __syncthreads();
  }
  const float M = rm[0];
  __syncthreads();
  float se = 0.0f;
#pragma unroll
  for (int q = 0; q < 4; ++q)
    se += __builtin_amdgcn_exp2f((sc[q] - M) * 1.4426950408889634f);
  rm[tid] = se;
  __syncthreads();
  for (int o = 128; o > 0; o >>= 1) {
    if (tid < o) rm[tid] += rm[tid+o];
    __syncthreads();
  }
  if (tid == 0) {
    const int n = ri[0];
    const float lse = M + logf(rm[0]);
    const float nlp = lp[b] + rs[0] - lse;
    lp[b] = nlp;
    mask[(size_t)b * NSQ + n] = NEGV;
    outv[step * BSZ + b] = (float)n;
    if (step == NSTEPC - 1) outv[NSTEPC * BSZ + b] = nlp;
    sel = n;
  }
  __syncthreads();
  const int n = sel;
  const float4* src = (const float4*)(ctx + ((size_t)b * NSQ + n) * IND);
  float4* dst = (float4*)(xh + (size_t)b * KXD);
  for (int d = tid; d < IND / 4; d += 256) dst[d] = src[d];
}

extern "C" void kernel_launch(void* const* d_in, const int* in_sizes, int n_in,
                              void* d_out, int out_size, void* d_ws, size_t ws_size,
                              hipStream_t stream) {
  const float* target_emb = (const float*)d_in[0];
  const float* ctx_emb   = (const float*)d_in[1];
  const int*   ctx_len   = (const int*)d_in[3];
  const float* W_ih = (const float*)d_in[5];
  const float* W_hh = (const float*)d_in[6];
  const float* b_ih = (const float*)d_in[7];
  const float* b_hh = (const float*)d_in[8];
  const float* W1c  = (const float*)d_in[9];
  const float* W1h  = (const float*)d_in[10];
  const float* b1   = (const float*)d_in[11];
  const float* w2   = (const float*)d_in[12];
  const float* b2   = (const float*)d_in[13];
  const float* gumbel = (const float*)d_in[14];
  float* out = (float*)d_out;

  float* ws = (float*)d_ws;
  size_t off = 0;
  auto alloc = [&](size_t n) { float* p = ws + off; off += (n + 63) & ~(size_t)63; return p; };

  float* cp   = alloc((size_t)BSZ * MLPD * NSQ);   // 268 MB
  float* gp   = alloc((size_t)KSG * BSZ * G4D);
  float* hpp  = alloc((size_t)KSH * BSZ * MLPD);
  float* psc  = alloc((size_t)BSZ * MSPLIT * NSQ);
  float* mask = alloc((size_t)BSZ * NSQ);
  float* xh   = alloc((size_t)BSZ * KXD);
  float* cst  = alloc((size_t)BSZ * HIDD);
  float* lp   = alloc(128);
  unsigned short* wfh = (unsigned short*)alloc(196608);   // 512x768 u16, frag-order
  unsigned short* wfl = (unsigned short*)alloc(196608);
  int* meta = (int*)alloc(1088);   // [0]=nact, [1..1024]=active rb list

  k_prep_wfrag<<<192, 256, 0, stream>>>(W1c, wfh, wfl);
  k_init<<<BSZ, 256, 0, stream>>>(target_emb, ctx_len, mask, xh, cst, lp);
  k_active<<<1, 256, 0, stream>>>(ctx_len, meta);
  k_ctx7<<<1024, 256, 0, stream>>>(ctx_emb, wfh, wfl, b1, meta, cp);

  for (int t = 0; t < NSTEPC; ++t) {
    // gates partials: N=2048, K=1280 split in 16 chunks of 5 tiles
    k_pgemm<<<dim3(G4D/128, KSG), 256, 0, stream>>>(
        xh, KXD, 0, W_ih, IND, IND, W_hh, HIDD, 5, G4D, gp);
    k_lstm<<<BSZ, 512, 0, stream>>>(gp, b_ih, b_hh, cst, xh);
    // hproj partials: N=512, K=512 split in 8 chunks of 4 tiles
    k_pgemm<<<dim3(MLPD/128, KSH), 256, 0, stream>>>(
        xh, KXD, IND, W1h, HIDD, 1 << 30, nullptr, 0, 4, MLPD, hpp);
    k_scores<<<dim3(MSPLIT, BSZ), 256, 0, stream>>>(cp, hpp, w2, ctx_len, psc);
    k_argmax<<<BSZ, 256, 0, stream>>>(psc, mask, gumbel, b2, lp, ctx_emb, xh, out, t);
  }
}